// Round 13
// baseline (129.920 us; speedup 1.0000x reference)
//
#include <hip/hip_runtime.h>
#include <hip/hip_bf16.h>

typedef unsigned short u16;
typedef __attribute__((ext_vector_type(8))) short bf16x8;
typedef __attribute__((ext_vector_type(8))) short short8;
typedef __attribute__((ext_vector_type(16))) float f32x16;

#define B_ 16
#define CIN 256
#define COUT 256
#define NPIX 4096
#define E_ 8
#define HP 66            // halo-padded width/height
#define PPIX (HP*HP)     // 4356 padded pixels per sample
#define KTOT 2304        // 9 * 256
#define NKT 36           // K-tiles of 64

__device__ __forceinline__ u16 f2bf(float f){
    union { float f; unsigned int u; } v; v.f = f;
    return (u16)((v.u + 0x7FFFu + ((v.u >> 16) & 1u)) >> 16);
}

__device__ __forceinline__ void gload(const u16* g, u16* l){
    __builtin_amdgcn_global_load_lds(
        (const __attribute__((address_space(1))) unsigned int*)g,
        (__attribute__((address_space(3))) unsigned int*)l, 16, 0, 0);
}

// -------- 1) transpose+convert x -> xt2[b][(y+1)*66+(x+1)][cin] bf16,
//            fused avg-pool partial sums + fused halo-border zeroing --------
__global__ void k_xt(const float* __restrict__ x, u16* __restrict__ xt2,
                     float* __restrict__ pooled){
    __shared__ float tile[64][65];
    int bid = blockIdx.x;
    int t = threadIdx.x;

    if (bid < 520){
        int gid = bid*256 + t;
        int u4 = gid & 31;
        int pl = gid >> 5;
        if (pl < B_*260){
            int bb = pl / 260;
            int pi = pl - bb*260;
            int yy, xx;
            if (pi < 66)      { yy = 0;  xx = pi; }
            else if (pi < 132){ yy = 65; xx = pi - 66; }
            else { int q = pi - 132; yy = 1 + (q >> 1); xx = (q & 1) ? 65 : 0; }
            uint4 z = {0u,0u,0u,0u};
            *(uint4*)(xt2 + ((size_t)bb*PPIX + yy*HP + xx)*CIN + u4*8) = z;
        }
    }

    int b = bid >> 8, ct = (bid >> 6) & 3, pt = bid & 63;
    int c0 = ct*64, p0 = pt*64;
    #pragma unroll
    for (int iter = 0; iter < 4; ++iter){
        int idx = t*4 + iter*1024;
        int r = idx >> 6, c4 = idx & 63;
        float4 v = *(const float4*)(x + ((size_t)(b*CIN + c0 + r))*NPIX + p0 + c4);
        tile[r][c4+0] = v.x; tile[r][c4+1] = v.y; tile[r][c4+2] = v.z; tile[r][c4+3] = v.w;
        float rs = v.x + v.y + v.z + v.w;
        #pragma unroll
        for (int off = 1; off < 16; off <<= 1) rs += __shfl_xor(rs, off, 64);
        if ((t & 15) == 0) atomicAdd(&pooled[b*CIN + c0 + r], rs);
    }
    __syncthreads();
    #pragma unroll
    for (int iter = 0; iter < 4; ++iter){
        int idx = t*4 + iter*1024;
        int pr = idx >> 6, cc = idx & 63;
        ushort4 u;
        u.x = f2bf(tile[cc+0][pr]);
        u.y = f2bf(tile[cc+1][pr]);
        u.z = f2bf(tile[cc+2][pr]);
        u.w = f2bf(tile[cc+3][pr]);
        int p = p0 + pr;
        int yy = p >> 6, xx = p & 63;
        *(ushort4*)(xt2 + ((size_t)b*PPIX + (yy+1)*HP + (xx+1))*CIN + c0 + cc) = u;
    }
}

// -------- 2) aggregated weights + routing + bias; vectorized short8 stores --------
__global__ __launch_bounds__(320) void k_aggw(
    const float* __restrict__ weight, const float* __restrict__ pooled,
    const float* __restrict__ rw, const float* __restrict__ rb,
    const float* __restrict__ bias,
    u16* __restrict__ aggw, float* __restrict__ aggb)
{
    __shared__ float wls[E_][2304];
    __shared__ float r_s[B_*E_];
    int o = blockIdx.x, t = threadIdx.x;

    if (t < B_*E_){
        int b = t >> 3, e = t & 7;
        const float4* pp = (const float4*)(pooled + b*CIN);
        const float4* wp = (const float4*)(rw + e*CIN);
        float s = 0.f;
        #pragma unroll
        for (int i = 0; i < 64; ++i){
            float4 a = pp[i], c = wp[i];
            s += a.x*c.x + a.y*c.y + a.z*c.z + a.w*c.w;
        }
        s = s * (1.0f/(float)NPIX) + rb[e];
        r_s[t] = 1.0f/(1.0f + __expf(-s));
    }
    #pragma unroll
    for (int e = 0; e < E_; ++e){
        const float4* src = (const float4*)(weight + ((size_t)(e*COUT + o))*2304);
        float4* dst = (float4*)wls[e];
        if (t < 576)       dst[t] = src[t];
        int i2 = t + 320;
        if (i2 < 576)      dst[i2] = src[i2];
    }
    __syncthreads();

    if (t < B_){
        float s = 0.f;
        #pragma unroll
        for (int e = 0; e < E_; ++e) s += r_s[t*E_+e]*bias[e*COUT+o];
        aggb[t*COUT + o] = s;
    }

    if (t < 288){
        int tp = t >> 5, cg = t & 31;
        float w[E_][8];
        #pragma unroll
        for (int e = 0; e < E_; ++e)
            #pragma unroll
            for (int j = 0; j < 8; ++j)
                w[e][j] = wls[e][(cg*8 + j)*9 + tp];

        for (int b = 0; b < B_; ++b){
            float acc[8];
            #pragma unroll
            for (int j = 0; j < 8; ++j) acc[j] = 0.f;
            #pragma unroll
            for (int e = 0; e < E_; ++e){
                float r = r_s[b*E_ + e];
                #pragma unroll
                for (int j = 0; j < 8; ++j) acc[j] += r * w[e][j];
            }
            short8 ov;
            #pragma unroll
            for (int jj = 0; jj < 4; ++jj){
                unsigned int d;
                asm("v_cvt_pk_bf16_f32 %0, %1, %2" : "=v"(d) : "v"(acc[2*jj]), "v"(acc[2*jj+1]));
                ov[2*jj]   = (short)(d & 0xFFFF);
                ov[2*jj+1] = (short)(d >> 16);
            }
            *(short8*)(aggw + (((size_t)(b*COUT + o))*9 + tp)*CIN + cg*8) = ov;
        }
    }
}

// -------- 3) k_conv: R4 skeleton, MFMA 32x32x16 --------
__global__ __launch_bounds__(512, 2) void k_conv(
    const u16* __restrict__ aggw, const u16* __restrict__ xt2,
    const float* __restrict__ aggb, float* __restrict__ out)
{
    __shared__ __align__(16) u16 lds[65536];   // 2 buf x (A 256x64 + B 256x64) bf16

    int orig = blockIdx.x;
    int bid = (orig & 7)*32 + (orig >> 3);     // bijective XCD swizzle

    int b  = bid >> 4;
    int nt = bid & 15;
    int y0 = nt << 2;

    int t = threadIdx.x;
    int lane = t & 63;
    int w = t >> 6;
    int wm = (w >> 2) << 7;      // 0 / 128
    int wn = (w & 3) << 6;       // 0 / 64 / 128 / 192
    int l31 = lane & 31;
    int lhi = lane >> 5;         // 0 / 1
    int swz = l31 & 7;

    // staging (unchanged, proven): thread t covers row tr, slot tc holding granule tc^(tr&7)
    int tr = t >> 3;
    int tc = t & 7;
    int sc = tc ^ (tr & 7);

    const u16* aSrc = aggw + (size_t)b*COUT*9*CIN + (size_t)tr*KTOT + sc*8;
    const u16* bSrc = xt2 + ((size_t)b*PPIX + (size_t)y0*HP + tr)*CIN + sc*8;

    f32x16 acc[8];               // frag (mb*2+nb): mb 0..3 (M=32 each), nb 0..1 (N=32 each)
    #pragma unroll
    for (int f = 0; f < 8; ++f)
        #pragma unroll
        for (int i = 0; i < 16; ++i) acc[f][i] = 0.f;

    auto stage = [&](int kt, int bufn){
        int tap = kt >> 2;
        int c0  = (kt & 3) << 6;
        int kh  = tap / 3, kw = tap - kh*3;
        const u16* a0 = aSrc + tap*CIN + c0;
        const u16* b0 = bSrc + (kh*HP + kw)*CIN + c0;
        u16* dA = lds + bufn*32768 + w*512;
        u16* dB = dA + 16384;
        #pragma unroll
        for (int i = 0; i < 4; ++i)
            gload(a0 + (size_t)i*64*KTOT, dA + i*4096);
        #pragma unroll
        for (int i = 0; i < 4; ++i)
            gload(b0 + (size_t)i*HP*CIN, dB + i*4096);
    };

    // read-side swizzled slot offsets (u16) per kstep: granule = 2*ks + lhi
    int cks0 = (((0 + lhi) ^ swz) << 3);
    int cks1 = (((2 + lhi) ^ swz) << 3);
    int cks2 = (((4 + lhi) ^ swz) << 3);
    int cks3 = (((6 + lhi) ^ swz) << 3);

    stage(0, 0);
    __syncthreads();

    int buf = 0;
    #pragma unroll 2
    for (int kt = 0; kt < NKT; ++kt){
        const u16* LA = lds + buf*32768;
        const u16* LB = LA + 16384;

        bf16x8 af[4][4];    // [ks][mb]
        bf16x8 bfv[4][2];   // [ks][nb]

        // first half of reads: A mb=0,1 (8) + B nb=0 (4)
        #pragma unroll
        for (int mb = 0; mb < 2; ++mb){
            int ro = (wm + mb*32 + l31) * 64;
            af[0][mb] = *(const bf16x8*)(LA + ro + cks0);
            af[1][mb] = *(const bf16x8*)(LA + ro + cks1);
            af[2][mb] = *(const bf16x8*)(LA + ro + cks2);
            af[3][mb] = *(const bf16x8*)(LA + ro + cks3);
        }
        {
            int ro = (wn + l31) * 64;
            bfv[0][0] = *(const bf16x8*)(LB + ro + cks0);
            bfv[1][0] = *(const bf16x8*)(LB + ro + cks1);
            bfv[2][0] = *(const bf16x8*)(LB + ro + cks2);
            bfv[3][0] = *(const bf16x8*)(LB + ro + cks3);
        }

        if (kt < NKT-1) stage(kt+1, buf^1);

        // second half of reads: B nb=1 (4) + A mb=2,3 (8)
        {
            int ro = (wn + 32 + l31) * 64;
            bfv[0][1] = *(const bf16x8*)(LB + ro + cks0);
            bfv[1][1] = *(const bf16x8*)(LB + ro + cks1);
            bfv[2][1] = *(const bf16x8*)(LB + ro + cks2);
            bfv[3][1] = *(const bf16x8*)(LB + ro + cks3);
        }
        #pragma unroll
        for (int mb = 2; mb < 4; ++mb){
            int ro = (wm + mb*32 + l31) * 64;
            af[0][mb] = *(const bf16x8*)(LA + ro + cks0);
            af[1][mb] = *(const bf16x8*)(LA + ro + cks1);
            af[2][mb] = *(const bf16x8*)(LA + ro + cks2);
            af[3][mb] = *(const bf16x8*)(LA + ro + cks3);
        }

        // 4 MFMA clusters: (mb-pair 0/1) x (nb 0/1), 8 MFMA each
        #pragma unroll
        for (int mq = 0; mq < 2; ++mq)
            #pragma unroll
            for (int nb = 0; nb < 2; ++nb){
                __builtin_amdgcn_s_setprio(1);
                #pragma unroll
                for (int m2 = 0; m2 < 2; ++m2){
                    int mb = mq*2 + m2;
                    int f = mb*2 + nb;
                    #pragma unroll
                    for (int ks = 0; ks < 4; ++ks)
                        acc[f] = __builtin_amdgcn_mfma_f32_32x32x16_bf16(
                            af[ks][mb], bfv[ks][nb], acc[f], 0, 0, 0);
                }
                __builtin_amdgcn_s_setprio(0);
            }

        __syncthreads();
        buf ^= 1;
    }

    // epilogue: C/D layout col=lane&31, row=(reg&3)+8*(reg>>2)+4*lhi
    const float* ab = aggb + b*COUT;
    float* outp = out + ((size_t)b*COUT)*NPIX + nt*256;
    #pragma unroll
    for (int mb = 0; mb < 4; ++mb)
        #pragma unroll
        for (int nb = 0; nb < 2; ++nb){
            int f = mb*2 + nb;
            #pragma unroll
            for (int i = 0; i < 16; ++i){
                int r = wm + mb*32 + (i & 3) + 8*(i >> 2) + 4*lhi;
                float* orow = outp + (size_t)r*NPIX;
                orow[wn + nb*32 + l31] = acc[f][i] + ab[r];
            }
        }
}

extern "C" void kernel_launch(void* const* d_in, const int* in_sizes, int n_in,
                              void* d_out, int out_size, void* d_ws, size_t ws_size,
                              hipStream_t stream)
{
    const float* x      = (const float*)d_in[0];
    const float* weight = (const float*)d_in[1];
    const float* bias   = (const float*)d_in[2];
    const float* rw     = (const float*)d_in[3];
    const float* rb     = (const float*)d_in[4];
    float* out = (float*)d_out;

    char* ws = (char*)d_ws;
    u16*   aggw    = (u16*)(ws);                          // 18,874,368 B
    u16*   xt2     = (u16*)(ws + 18874368);               // 35,684,352 B (halo 66x66)
    float* pooled  = (float*)(ws + 54558720);             // 16 KB
    float* aggb    = (float*)(ws + 54558720 + 16384);     // 16 KB

    hipMemsetAsync(pooled, 0, B_*CIN*sizeof(float), stream);
    k_xt   <<<4096, 256, 0, stream>>>(x, xt2, pooled);
    k_aggw <<<COUT, 320, 0, stream>>>(weight, pooled, rw, rb, bias, aggw, aggb);
    k_conv <<<256,  512, 0, stream>>>(aggw, xt2, aggb, out);
}

// Round 14
// 119.545 us; speedup vs baseline: 1.0868x; 1.0868x over previous
//
#include <hip/hip_runtime.h>
#include <hip/hip_bf16.h>

typedef unsigned short u16;
typedef __attribute__((ext_vector_type(8))) short bf16x8;
typedef __attribute__((ext_vector_type(8))) short short8;
typedef __attribute__((ext_vector_type(4))) float f32x4;

#define B_ 16
#define CIN 256
#define COUT 256
#define NPIX 4096
#define E_ 8
#define HP 66            // halo-padded width/height
#define PPIX (HP*HP)     // 4356 padded pixels per sample
#define KTOT 2304        // 9 * 256
#define NKT 36           // K-tiles of 64

__device__ __forceinline__ u16 f2bf(float f){
    union { float f; unsigned int u; } v; v.f = f;
    return (u16)((v.u + 0x7FFFu + ((v.u >> 16) & 1u)) >> 16);
}

__device__ __forceinline__ void gload(const u16* g, u16* l){
    __builtin_amdgcn_global_load_lds(
        (const __attribute__((address_space(1))) unsigned int*)g,
        (__attribute__((address_space(3))) unsigned int*)l, 16, 0, 0);
}

// -------- 1) transpose+convert x -> xt2[b][(y+1)*66+(x+1)][cin] bf16,
//            fused avg-pool partial sums + fused halo-border zeroing; 16B stores --------
__global__ void k_xt(const float* __restrict__ x, u16* __restrict__ xt2,
                     float* __restrict__ pooled){
    __shared__ float tile[64][65];
    int bid = blockIdx.x;
    int t = threadIdx.x;

    if (bid < 520){
        int gid = bid*256 + t;
        int u4 = gid & 31;
        int pl = gid >> 5;
        if (pl < B_*260){
            int bb = pl / 260;
            int pi = pl - bb*260;
            int yy, xx;
            if (pi < 66)      { yy = 0;  xx = pi; }
            else if (pi < 132){ yy = 65; xx = pi - 66; }
            else { int q = pi - 132; yy = 1 + (q >> 1); xx = (q & 1) ? 65 : 0; }
            uint4 z = {0u,0u,0u,0u};
            *(uint4*)(xt2 + ((size_t)bb*PPIX + yy*HP + xx)*CIN + u4*8) = z;
        }
    }

    int b = bid >> 8, ct = (bid >> 6) & 3, pt = bid & 63;
    int c0 = ct*64, p0 = pt*64;
    #pragma unroll
    for (int iter = 0; iter < 4; ++iter){
        int idx = t*4 + iter*1024;
        int r = idx >> 6, c4 = idx & 63;
        float4 v = *(const float4*)(x + ((size_t)(b*CIN + c0 + r))*NPIX + p0 + c4);
        tile[r][c4+0] = v.x; tile[r][c4+1] = v.y; tile[r][c4+2] = v.z; tile[r][c4+3] = v.w;
        float rs = v.x + v.y + v.z + v.w;
        #pragma unroll
        for (int off = 1; off < 16; off <<= 1) rs += __shfl_xor(rs, off, 64);
        if ((t & 15) == 0) atomicAdd(&pooled[b*CIN + c0 + r], rs);
    }
    __syncthreads();
    // write: unit = (g_l 0..7, px 0..63); 16B short8 store of 8 consecutive cin
    #pragma unroll
    for (int iter = 0; iter < 2; ++iter){
        int unit = t + iter*256;
        int g_l = unit >> 6, pr = unit & 63;
        short8 o;
        #pragma unroll
        for (int i = 0; i < 8; ++i) o[i] = (short)f2bf(tile[g_l*8 + i][pr]);
        int p = p0 + pr;
        int yy = p >> 6, xx = p & 63;
        *(short8*)(xt2 + ((size_t)b*PPIX + (yy+1)*HP + (xx+1))*CIN + c0 + g_l*8) = o;
    }
}

// -------- 2) aggregated weights: 576 threads, batch split across two thread groups --------
__global__ __launch_bounds__(576) void k_aggw(
    const float* __restrict__ weight, const float* __restrict__ pooled,
    const float* __restrict__ rw, const float* __restrict__ rb,
    const float* __restrict__ bias,
    u16* __restrict__ aggw, float* __restrict__ aggb)
{
    __shared__ float wls[E_][2304];
    __shared__ float r_s[B_*E_];
    int o = blockIdx.x, t = threadIdx.x;

    if (t < B_*E_){
        int b = t >> 3, e = t & 7;
        const float4* pp = (const float4*)(pooled + b*CIN);
        const float4* wp = (const float4*)(rw + e*CIN);
        float s = 0.f;
        #pragma unroll
        for (int i = 0; i < 64; ++i){
            float4 a = pp[i], c = wp[i];
            s += a.x*c.x + a.y*c.y + a.z*c.z + a.w*c.w;
        }
        s = s * (1.0f/(float)NPIX) + rb[e];
        r_s[t] = 1.0f/(1.0f + __expf(-s));
    }
    #pragma unroll
    for (int e = 0; e < E_; ++e){
        const float4* src = (const float4*)(weight + ((size_t)(e*COUT + o))*2304);
        float4* dst = (float4*)wls[e];
        dst[t] = src[t];        // 576 threads = exactly 576 float4
    }
    __syncthreads();

    if (t < B_){
        float s = 0.f;
        #pragma unroll
        for (int e = 0; e < E_; ++e) s += r_s[t*E_+e]*bias[e*COUT+o];
        aggb[t*COUT + o] = s;
    }

    // two groups of 288: group g handles b = g*8 .. g*8+7
    {
        int grp = (t >= 288);
        int u = t - grp*288;
        int tp = u >> 5, cg = u & 31;
        float w[E_][8];
        #pragma unroll
        for (int e = 0; e < E_; ++e)
            #pragma unroll
            for (int j = 0; j < 8; ++j)
                w[e][j] = wls[e][(cg*8 + j)*9 + tp];

        int b0 = grp*8;
        for (int bb = 0; bb < 8; ++bb){
            int b = b0 + bb;
            float acc[8];
            #pragma unroll
            for (int j = 0; j < 8; ++j) acc[j] = 0.f;
            #pragma unroll
            for (int e = 0; e < E_; ++e){
                float r = r_s[b*E_ + e];
                #pragma unroll
                for (int j = 0; j < 8; ++j) acc[j] += r * w[e][j];
            }
            short8 ov;
            #pragma unroll
            for (int jj = 0; jj < 4; ++jj){
                unsigned int d;
                asm("v_cvt_pk_bf16_f32 %0, %1, %2" : "=v"(d) : "v"(acc[2*jj]), "v"(acc[2*jj+1]));
                ov[2*jj]   = (short)(d & 0xFFFF);
                ov[2*jj+1] = (short)(d >> 16);
            }
            *(short8*)(aggw + (((size_t)(b*COUT + o))*9 + tp)*CIN + cg*8) = ov;
        }
    }
}

// -------- 3) k_conv: VERBATIM R4/R12 (best measured: 77.3 us) --------
__global__ __launch_bounds__(512, 2) void k_conv(
    const u16* __restrict__ aggw, const u16* __restrict__ xt2,
    const float* __restrict__ aggb, float* __restrict__ out)
{
    __shared__ __align__(16) u16 lds[65536];   // 2 buf x (A 256x64 + B 256x64) bf16

    int orig = blockIdx.x;
    int bid = (orig & 7)*32 + (orig >> 3);     // bijective XCD swizzle

    int b  = bid >> 4;
    int nt = bid & 15;
    int y0 = nt << 2;

    int t = threadIdx.x;
    int lane = t & 63;
    int w = t >> 6;
    int wm = (w >> 2) << 7;
    int wn = (w & 3) << 6;
    int l16 = lane & 15;
    int kh4 = lane >> 4;
    int sw  = l16 & 7;

    int tr = t >> 3;
    int tc = t & 7;
    int sc = tc ^ (tr & 7);

    const u16* aSrc = aggw + (size_t)b*COUT*9*CIN + (size_t)tr*KTOT + sc*8;
    const u16* bSrc = xt2 + ((size_t)b*PPIX + (size_t)y0*HP + tr)*CIN + sc*8;

    f32x4 acc[8][4];
    #pragma unroll
    for (int i = 0; i < 8; ++i)
        #pragma unroll
        for (int j = 0; j < 4; ++j){
            f32x4 z = {0.f,0.f,0.f,0.f};
            acc[i][j] = z;
        }

    auto stage = [&](int kt, int bufn){
        int tap = kt >> 2;
        int c0  = (kt & 3) << 6;
        int kh  = tap / 3, kw = tap - kh*3;
        const u16* a0 = aSrc + tap*CIN + c0;
        const u16* b0 = bSrc + (kh*HP + kw)*CIN + c0;
        u16* dA = lds + bufn*32768 + w*512;
        u16* dB = dA + 16384;
        #pragma unroll
        for (int i = 0; i < 4; ++i)
            gload(a0 + (size_t)i*64*KTOT, dA + i*4096);
        #pragma unroll
        for (int i = 0; i < 4; ++i)
            gload(b0 + (size_t)i*HP*CIN, dB + i*4096);
    };

    int ck0 = ((kh4    ) ^ sw) * 8;
    int ck1 = ((kh4 | 4) ^ sw) * 8;

    stage(0, 0);
    __syncthreads();

    int buf = 0;
    #pragma unroll 2
    for (int kt = 0; kt < NKT; ++kt){
        const u16* LA = lds + buf*32768;
        const u16* LB = LA + 16384;

        bf16x8 af[2][4][2];    // [qm][mf][khalf]
        bf16x8 bfr[2][2][2];   // [qn][nf][khalf]

        #pragma unroll
        for (int mf = 0; mf < 4; ++mf){
            int ro = (wm + mf*16 + l16) * 64;
            af[0][mf][0] = *(const bf16x8*)(LA + ro + ck0);
            af[0][mf][1] = *(const bf16x8*)(LA + ro + ck1);
        }
        #pragma unroll
        for (int nf = 0; nf < 2; ++nf){
            int ro = (wn + nf*16 + l16) * 64;
            bfr[0][nf][0] = *(const bf16x8*)(LB + ro + ck0);
            bfr[0][nf][1] = *(const bf16x8*)(LB + ro + ck1);
        }

        if (kt < NKT-1) stage(kt+1, buf^1);

        #pragma unroll
        for (int nf = 0; nf < 2; ++nf){
            int ro = (wn + 32 + nf*16 + l16) * 64;
            bfr[1][nf][0] = *(const bf16x8*)(LB + ro + ck0);
            bfr[1][nf][1] = *(const bf16x8*)(LB + ro + ck1);
        }
        #pragma unroll
        for (int mf = 0; mf < 4; ++mf){
            int ro = (wm + 64 + mf*16 + l16) * 64;
            af[1][mf][0] = *(const bf16x8*)(LA + ro + ck0);
            af[1][mf][1] = *(const bf16x8*)(LA + ro + ck1);
        }

        #pragma unroll
        for (int qm = 0; qm < 2; ++qm)
            #pragma unroll
            for (int qn = 0; qn < 2; ++qn){
                __builtin_amdgcn_s_setprio(1);
                #pragma unroll
                for (int mf = 0; mf < 4; ++mf)
                    #pragma unroll
                    for (int nf = 0; nf < 2; ++nf){
                        acc[qm*4+mf][qn*2+nf] = __builtin_amdgcn_mfma_f32_16x16x32_bf16(
                            af[qm][mf][0], bfr[qn][nf][0], acc[qm*4+mf][qn*2+nf], 0, 0, 0);
                        acc[qm*4+mf][qn*2+nf] = __builtin_amdgcn_mfma_f32_16x16x32_bf16(
                            af[qm][mf][1], bfr[qn][nf][1], acc[qm*4+mf][qn*2+nf], 0, 0, 0);
                    }
                __builtin_amdgcn_s_setprio(0);
            }

        __syncthreads();
        buf ^= 1;
    }

    const float* ab = aggb + b*COUT;
    float* outp = out + ((size_t)b*COUT)*NPIX + nt*256;
    #pragma unroll
    for (int mf8 = 0; mf8 < 8; ++mf8){
        #pragma unroll
        for (int v = 0; v < 4; ++v){
            int r = wm + mf8*16 + (kh4 << 2) + v;
            float bias_r = ab[r];
            float* orow = outp + (size_t)r*NPIX;
            #pragma unroll
            for (int nf = 0; nf < 4; ++nf)
                orow[wn + nf*16 + l16] = acc[mf8][nf][v] + bias_r;
        }
    }
}

extern "C" void kernel_launch(void* const* d_in, const int* in_sizes, int n_in,
                              void* d_out, int out_size, void* d_ws, size_t ws_size,
                              hipStream_t stream)
{
    const float* x      = (const float*)d_in[0];
    const float* weight = (const float*)d_in[1];
    const float* bias   = (const float*)d_in[2];
    const float* rw     = (const float*)d_in[3];
    const float* rb     = (const float*)d_in[4];
    float* out = (float*)d_out;

    char* ws = (char*)d_ws;
    u16*   aggw    = (u16*)(ws);                          // 18,874,368 B
    u16*   xt2     = (u16*)(ws + 18874368);               // 35,684,352 B (halo 66x66)
    float* pooled  = (float*)(ws + 54558720);             // 16 KB
    float* aggb    = (float*)(ws + 54558720 + 16384);     // 16 KB

    hipMemsetAsync(pooled, 0, B_*CIN*sizeof(float), stream);
    k_xt   <<<4096, 256, 0, stream>>>(x, xt2, pooled);
    k_aggw <<<COUT, 576, 0, stream>>>(weight, pooled, rw, rb, bias, aggw, aggb);
    k_conv <<<256,  512, 0, stream>>>(aggw, xt2, aggb, out);
}

// Round 15
// 115.137 us; speedup vs baseline: 1.1284x; 1.0383x over previous
//
#include <hip/hip_runtime.h>
#include <hip/hip_bf16.h>

typedef unsigned short u16;
typedef __attribute__((ext_vector_type(8))) short bf16x8;
typedef __attribute__((ext_vector_type(8))) short short8;
typedef __attribute__((ext_vector_type(4))) float f32x4;

#define B_ 16
#define CIN 256
#define COUT 256
#define NPIX 4096
#define E_ 8
#define HP 66            // halo-padded width/height
#define PPIX (HP*HP)     // 4356 padded pixels per sample
#define KTOT 2304        // 9 * 256
#define NKT 36           // K-tiles of 64

__device__ __forceinline__ u16 f2bf(float f){
    union { float f; unsigned int u; } v; v.f = f;
    return (u16)((v.u + 0x7FFFu + ((v.u >> 16) & 1u)) >> 16);
}

__device__ __forceinline__ void gload(const u16* g, u16* l){
    __builtin_amdgcn_global_load_lds(
        (const __attribute__((address_space(1))) unsigned int*)g,
        (__attribute__((address_space(3))) unsigned int*)l, 16, 0, 0);
}

// -------- 1) transpose+convert x -> xt2[b][(y+1)*66+(x+1)][cin] bf16,
//            fused pool + border-zero; COALESCED short8 stores + cvt_pk --------
__global__ void k_xt(const float* __restrict__ x, u16* __restrict__ xt2,
                     float* __restrict__ pooled){
    __shared__ float tile[64][65];
    int bid = blockIdx.x;
    int t = threadIdx.x;

    if (bid < 520){
        int gid = bid*256 + t;
        int u4 = gid & 31;
        int pl = gid >> 5;
        if (pl < B_*260){
            int bb = pl / 260;
            int pi = pl - bb*260;
            int yy, xx;
            if (pi < 66)      { yy = 0;  xx = pi; }
            else if (pi < 132){ yy = 65; xx = pi - 66; }
            else { int q = pi - 132; yy = 1 + (q >> 1); xx = (q & 1) ? 65 : 0; }
            uint4 z = {0u,0u,0u,0u};
            *(uint4*)(xt2 + ((size_t)bb*PPIX + yy*HP + xx)*CIN + u4*8) = z;
        }
    }

    int b = bid >> 8, ct = (bid >> 6) & 3, pt = bid & 63;
    int c0 = ct*64, p0 = pt*64;
    #pragma unroll
    for (int iter = 0; iter < 4; ++iter){
        int idx = t*4 + iter*1024;
        int r = idx >> 6, c4 = idx & 63;
        float4 v = *(const float4*)(x + ((size_t)(b*CIN + c0 + r))*NPIX + p0 + c4);
        tile[r][c4+0] = v.x; tile[r][c4+1] = v.y; tile[r][c4+2] = v.z; tile[r][c4+3] = v.w;
        float rs = v.x + v.y + v.z + v.w;
        #pragma unroll
        for (int off = 1; off < 16; off <<= 1) rs += __shfl_xor(rs, off, 64);
        if ((t & 15) == 0) atomicAdd(&pooled[b*CIN + c0 + r], rs);
    }
    __syncthreads();
    // pass 2: unit = (pr, g_l); 8 consecutive lanes (g_l 0..7) write one pixel's
    // 128B c-chunk contiguously -> 8x128B segments per wave-instr. 4 cvt_pk per store.
    #pragma unroll
    for (int iter = 0; iter < 2; ++iter){
        int unit = t + iter*256;
        int g_l = unit & 7, pr = unit >> 3;
        unsigned int d0, d1, d2, d3;
        asm("v_cvt_pk_bf16_f32 %0, %1, %2" : "=v"(d0)
            : "v"(tile[g_l*8+0][pr]), "v"(tile[g_l*8+1][pr]));
        asm("v_cvt_pk_bf16_f32 %0, %1, %2" : "=v"(d1)
            : "v"(tile[g_l*8+2][pr]), "v"(tile[g_l*8+3][pr]));
        asm("v_cvt_pk_bf16_f32 %0, %1, %2" : "=v"(d2)
            : "v"(tile[g_l*8+4][pr]), "v"(tile[g_l*8+5][pr]));
        asm("v_cvt_pk_bf16_f32 %0, %1, %2" : "=v"(d3)
            : "v"(tile[g_l*8+6][pr]), "v"(tile[g_l*8+7][pr]));
        uint4 o; o.x = d0; o.y = d1; o.z = d2; o.w = d3;
        int p = p0 + pr;
        int yy = p >> 6, xx = p & 63;
        *(uint4*)(xt2 + ((size_t)b*PPIX + (yy+1)*HP + (xx+1))*CIN + c0 + g_l*8) = o;
    }
}

// -------- 2) aggregated weights: 576 threads, batch split across two thread groups --------
__global__ __launch_bounds__(576) void k_aggw(
    const float* __restrict__ weight, const float* __restrict__ pooled,
    const float* __restrict__ rw, const float* __restrict__ rb,
    const float* __restrict__ bias,
    u16* __restrict__ aggw, float* __restrict__ aggb)
{
    __shared__ float wls[E_][2304];
    __shared__ float r_s[B_*E_];
    int o = blockIdx.x, t = threadIdx.x;

    if (t < B_*E_){
        int b = t >> 3, e = t & 7;
        const float4* pp = (const float4*)(pooled + b*CIN);
        const float4* wp = (const float4*)(rw + e*CIN);
        float s = 0.f;
        #pragma unroll
        for (int i = 0; i < 64; ++i){
            float4 a = pp[i], c = wp[i];
            s += a.x*c.x + a.y*c.y + a.z*c.z + a.w*c.w;
        }
        s = s * (1.0f/(float)NPIX) + rb[e];
        r_s[t] = 1.0f/(1.0f + __expf(-s));
    }
    #pragma unroll
    for (int e = 0; e < E_; ++e){
        const float4* src = (const float4*)(weight + ((size_t)(e*COUT + o))*2304);
        float4* dst = (float4*)wls[e];
        dst[t] = src[t];        // 576 threads = exactly 576 float4
    }
    __syncthreads();

    if (t < B_){
        float s = 0.f;
        #pragma unroll
        for (int e = 0; e < E_; ++e) s += r_s[t*E_+e]*bias[e*COUT+o];
        aggb[t*COUT + o] = s;
    }

    {
        int grp = (t >= 288);
        int u = t - grp*288;
        int tp = u >> 5, cg = u & 31;
        float w[E_][8];
        #pragma unroll
        for (int e = 0; e < E_; ++e)
            #pragma unroll
            for (int j = 0; j < 8; ++j)
                w[e][j] = wls[e][(cg*8 + j)*9 + tp];

        int b0 = grp*8;
        for (int bb = 0; bb < 8; ++bb){
            int b = b0 + bb;
            float acc[8];
            #pragma unroll
            for (int j = 0; j < 8; ++j) acc[j] = 0.f;
            #pragma unroll
            for (int e = 0; e < E_; ++e){
                float r = r_s[b*E_ + e];
                #pragma unroll
                for (int j = 0; j < 8; ++j) acc[j] += r * w[e][j];
            }
            short8 ov;
            #pragma unroll
            for (int jj = 0; jj < 4; ++jj){
                unsigned int d;
                asm("v_cvt_pk_bf16_f32 %0, %1, %2" : "=v"(d) : "v"(acc[2*jj]), "v"(acc[2*jj+1]));
                ov[2*jj]   = (short)(d & 0xFFFF);
                ov[2*jj+1] = (short)(d >> 16);
            }
            *(short8*)(aggw + (((size_t)(b*COUT + o))*9 + tp)*CIN + cg*8) = ov;
        }
    }
}

// -------- 3) k_conv: VERBATIM R4/R12 (best measured: 77.3 us) --------
__global__ __launch_bounds__(512, 2) void k_conv(
    const u16* __restrict__ aggw, const u16* __restrict__ xt2,
    const float* __restrict__ aggb, float* __restrict__ out)
{
    __shared__ __align__(16) u16 lds[65536];   // 2 buf x (A 256x64 + B 256x64) bf16

    int orig = blockIdx.x;
    int bid = (orig & 7)*32 + (orig >> 3);     // bijective XCD swizzle

    int b  = bid >> 4;
    int nt = bid & 15;
    int y0 = nt << 2;

    int t = threadIdx.x;
    int lane = t & 63;
    int w = t >> 6;
    int wm = (w >> 2) << 7;
    int wn = (w & 3) << 6;
    int l16 = lane & 15;
    int kh4 = lane >> 4;
    int sw  = l16 & 7;

    int tr = t >> 3;
    int tc = t & 7;
    int sc = tc ^ (tr & 7);

    const u16* aSrc = aggw + (size_t)b*COUT*9*CIN + (size_t)tr*KTOT + sc*8;
    const u16* bSrc = xt2 + ((size_t)b*PPIX + (size_t)y0*HP + tr)*CIN + sc*8;

    f32x4 acc[8][4];
    #pragma unroll
    for (int i = 0; i < 8; ++i)
        #pragma unroll
        for (int j = 0; j < 4; ++j){
            f32x4 z = {0.f,0.f,0.f,0.f};
            acc[i][j] = z;
        }

    auto stage = [&](int kt, int bufn){
        int tap = kt >> 2;
        int c0  = (kt & 3) << 6;
        int kh  = tap / 3, kw = tap - kh*3;
        const u16* a0 = aSrc + tap*CIN + c0;
        const u16* b0 = bSrc + (kh*HP + kw)*CIN + c0;
        u16* dA = lds + bufn*32768 + w*512;
        u16* dB = dA + 16384;
        #pragma unroll
        for (int i = 0; i < 4; ++i)
            gload(a0 + (size_t)i*64*KTOT, dA + i*4096);
        #pragma unroll
        for (int i = 0; i < 4; ++i)
            gload(b0 + (size_t)i*HP*CIN, dB + i*4096);
    };

    int ck0 = ((kh4    ) ^ sw) * 8;
    int ck1 = ((kh4 | 4) ^ sw) * 8;

    stage(0, 0);
    __syncthreads();

    int buf = 0;
    #pragma unroll 2
    for (int kt = 0; kt < NKT; ++kt){
        const u16* LA = lds + buf*32768;
        const u16* LB = LA + 16384;

        bf16x8 af[2][4][2];    // [qm][mf][khalf]
        bf16x8 bfr[2][2][2];   // [qn][nf][khalf]

        #pragma unroll
        for (int mf = 0; mf < 4; ++mf){
            int ro = (wm + mf*16 + l16) * 64;
            af[0][mf][0] = *(const bf16x8*)(LA + ro + ck0);
            af[0][mf][1] = *(const bf16x8*)(LA + ro + ck1);
        }
        #pragma unroll
        for (int nf = 0; nf < 2; ++nf){
            int ro = (wn + nf*16 + l16) * 64;
            bfr[0][nf][0] = *(const bf16x8*)(LB + ro + ck0);
            bfr[0][nf][1] = *(const bf16x8*)(LB + ro + ck1);
        }

        if (kt < NKT-1) stage(kt+1, buf^1);

        #pragma unroll
        for (int nf = 0; nf < 2; ++nf){
            int ro = (wn + 32 + nf*16 + l16) * 64;
            bfr[1][nf][0] = *(const bf16x8*)(LB + ro + ck0);
            bfr[1][nf][1] = *(const bf16x8*)(LB + ro + ck1);
        }
        #pragma unroll
        for (int mf = 0; mf < 4; ++mf){
            int ro = (wm + 64 + mf*16 + l16) * 64;
            af[1][mf][0] = *(const bf16x8*)(LA + ro + ck0);
            af[1][mf][1] = *(const bf16x8*)(LA + ro + ck1);
        }

        #pragma unroll
        for (int qm = 0; qm < 2; ++qm)
            #pragma unroll
            for (int qn = 0; qn < 2; ++qn){
                __builtin_amdgcn_s_setprio(1);
                #pragma unroll
                for (int mf = 0; mf < 4; ++mf)
                    #pragma unroll
                    for (int nf = 0; nf < 2; ++nf){
                        acc[qm*4+mf][qn*2+nf] = __builtin_amdgcn_mfma_f32_16x16x32_bf16(
                            af[qm][mf][0], bfr[qn][nf][0], acc[qm*4+mf][qn*2+nf], 0, 0, 0);
                        acc[qm*4+mf][qn*2+nf] = __builtin_amdgcn_mfma_f32_16x16x32_bf16(
                            af[qm][mf][1], bfr[qn][nf][1], acc[qm*4+mf][qn*2+nf], 0, 0, 0);
                    }
                __builtin_amdgcn_s_setprio(0);
            }

        __syncthreads();
        buf ^= 1;
    }

    const float* ab = aggb + b*COUT;
    float* outp = out + ((size_t)b*COUT)*NPIX + nt*256;
    #pragma unroll
    for (int mf8 = 0; mf8 < 8; ++mf8){
        #pragma unroll
        for (int v = 0; v < 4; ++v){
            int r = wm + mf8*16 + (kh4 << 2) + v;
            float bias_r = ab[r];
            float* orow = outp + (size_t)r*NPIX;
            #pragma unroll
            for (int nf = 0; nf < 4; ++nf)
                orow[wn + nf*16 + l16] = acc[mf8][nf][v] + bias_r;
        }
    }
}

extern "C" void kernel_launch(void* const* d_in, const int* in_sizes, int n_in,
                              void* d_out, int out_size, void* d_ws, size_t ws_size,
                              hipStream_t stream)
{
    const float* x      = (const float*)d_in[0];
    const float* weight = (const float*)d_in[1];
    const float* bias   = (const float*)d_in[2];
    const float* rw     = (const float*)d_in[3];
    const float* rb     = (const float*)d_in[4];
    float* out = (float*)d_out;

    char* ws = (char*)d_ws;
    u16*   aggw    = (u16*)(ws);                          // 18,874,368 B
    u16*   xt2     = (u16*)(ws + 18874368);               // 35,684,352 B (halo 66x66)
    float* pooled  = (float*)(ws + 54558720);             // 16 KB
    float* aggb    = (float*)(ws + 54558720 + 16384);     // 16 KB

    hipMemsetAsync(pooled, 0, B_*CIN*sizeof(float), stream);
    k_xt   <<<4096, 256, 0, stream>>>(x, xt2, pooled);
    k_aggw <<<COUT, 576, 0, stream>>>(weight, pooled, rw, rb, bias, aggw, aggb);
    k_conv <<<256,  512, 0, stream>>>(aggw, xt2, aggb, out);
}

// Round 16
// 113.564 us; speedup vs baseline: 1.1440x; 1.0139x over previous
//
#include <hip/hip_runtime.h>
#include <hip/hip_bf16.h>

typedef unsigned short u16;
typedef __attribute__((ext_vector_type(8))) short bf16x8;
typedef __attribute__((ext_vector_type(8))) short short8;
typedef __attribute__((ext_vector_type(4))) float f32x4;

#define B_ 16
#define CIN 256
#define COUT 256
#define NPIX 4096
#define E_ 8
#define HP 66            // halo-padded width/height
#define PPIX (HP*HP)     // 4356 padded pixels per sample
#define KTOT 2304        // 9 * 256
#define NKT 36           // K-tiles of 64

__device__ __forceinline__ u16 f2bf(float f){
    union { float f; unsigned int u; } v; v.f = f;
    return (u16)((v.u + 0x7FFFu + ((v.u >> 16) & 1u)) >> 16);
}

__device__ __forceinline__ void gload(const u16* g, u16* l){
    __builtin_amdgcn_global_load_lds(
        (const __attribute__((address_space(1))) unsigned int*)g,
        (__attribute__((address_space(3))) unsigned int*)l, 16, 0, 0);
}

// -------- 1) transpose+convert x -> xt2[b][(y+1)*66+(x+1)][cin] bf16,
//            fused pool + border-zero; coalesced uint4 stores + cvt_pk --------
__global__ void k_xt(const float* __restrict__ x, u16* __restrict__ xt2,
                     float* __restrict__ pooled){
    __shared__ float tile[64][65];
    int bid = blockIdx.x;
    int t = threadIdx.x;

    if (bid < 520){
        int gid = bid*256 + t;
        int u4 = gid & 31;
        int pl = gid >> 5;
        if (pl < B_*260){
            int bb = pl / 260;
            int pi = pl - bb*260;
            int yy, xx;
            if (pi < 66)      { yy = 0;  xx = pi; }
            else if (pi < 132){ yy = 65; xx = pi - 66; }
            else { int q = pi - 132; yy = 1 + (q >> 1); xx = (q & 1) ? 65 : 0; }
            uint4 z = {0u,0u,0u,0u};
            *(uint4*)(xt2 + ((size_t)bb*PPIX + yy*HP + xx)*CIN + u4*8) = z;
        }
    }

    int b = bid >> 8, ct = (bid >> 6) & 3, pt = bid & 63;
    int c0 = ct*64, p0 = pt*64;
    #pragma unroll
    for (int iter = 0; iter < 4; ++iter){
        int idx = t*4 + iter*1024;
        int r = idx >> 6, c4 = idx & 63;
        float4 v = *(const float4*)(x + ((size_t)(b*CIN + c0 + r))*NPIX + p0 + c4);
        tile[r][c4+0] = v.x; tile[r][c4+1] = v.y; tile[r][c4+2] = v.z; tile[r][c4+3] = v.w;
        float rs = v.x + v.y + v.z + v.w;
        #pragma unroll
        for (int off = 1; off < 16; off <<= 1) rs += __shfl_xor(rs, off, 64);
        if ((t & 15) == 0) atomicAdd(&pooled[b*CIN + c0 + r], rs);
    }
    __syncthreads();
    #pragma unroll
    for (int iter = 0; iter < 2; ++iter){
        int unit = t + iter*256;
        int g_l = unit & 7, pr = unit >> 3;
        unsigned int d0, d1, d2, d3;
        asm("v_cvt_pk_bf16_f32 %0, %1, %2" : "=v"(d0)
            : "v"(tile[g_l*8+0][pr]), "v"(tile[g_l*8+1][pr]));
        asm("v_cvt_pk_bf16_f32 %0, %1, %2" : "=v"(d1)
            : "v"(tile[g_l*8+2][pr]), "v"(tile[g_l*8+3][pr]));
        asm("v_cvt_pk_bf16_f32 %0, %1, %2" : "=v"(d2)
            : "v"(tile[g_l*8+4][pr]), "v"(tile[g_l*8+5][pr]));
        asm("v_cvt_pk_bf16_f32 %0, %1, %2" : "=v"(d3)
            : "v"(tile[g_l*8+6][pr]), "v"(tile[g_l*8+7][pr]));
        uint4 o; o.x = d0; o.y = d1; o.z = d2; o.w = d3;
        int p = p0 + pr;
        int yy = p >> 6, xx = p & 63;
        *(uint4*)(xt2 + ((size_t)b*PPIX + (yy+1)*HP + (xx+1))*CIN + c0 + g_l*8) = o;
    }
}

// -------- 2) aggregated weights: 576 threads, batch split across two thread groups --------
__global__ __launch_bounds__(576) void k_aggw(
    const float* __restrict__ weight, const float* __restrict__ pooled,
    const float* __restrict__ rw, const float* __restrict__ rb,
    const float* __restrict__ bias,
    u16* __restrict__ aggw, float* __restrict__ aggb)
{
    __shared__ float wls[E_][2304];
    __shared__ float r_s[B_*E_];
    int o = blockIdx.x, t = threadIdx.x;

    if (t < B_*E_){
        int b = t >> 3, e = t & 7;
        const float4* pp = (const float4*)(pooled + b*CIN);
        const float4* wp = (const float4*)(rw + e*CIN);
        float s = 0.f;
        #pragma unroll
        for (int i = 0; i < 64; ++i){
            float4 a = pp[i], c = wp[i];
            s += a.x*c.x + a.y*c.y + a.z*c.z + a.w*c.w;
        }
        s = s * (1.0f/(float)NPIX) + rb[e];
        r_s[t] = 1.0f/(1.0f + __expf(-s));
    }
    #pragma unroll
    for (int e = 0; e < E_; ++e){
        const float4* src = (const float4*)(weight + ((size_t)(e*COUT + o))*2304);
        float4* dst = (float4*)wls[e];
        dst[t] = src[t];
    }
    __syncthreads();

    if (t < B_){
        float s = 0.f;
        #pragma unroll
        for (int e = 0; e < E_; ++e) s += r_s[t*E_+e]*bias[e*COUT+o];
        aggb[t*COUT + o] = s;
    }

    {
        int grp = (t >= 288);
        int u = t - grp*288;
        int tp = u >> 5, cg = u & 31;
        float w[E_][8];
        #pragma unroll
        for (int e = 0; e < E_; ++e)
            #pragma unroll
            for (int j = 0; j < 8; ++j)
                w[e][j] = wls[e][(cg*8 + j)*9 + tp];

        int b0 = grp*8;
        for (int bb = 0; bb < 8; ++bb){
            int b = b0 + bb;
            float acc[8];
            #pragma unroll
            for (int j = 0; j < 8; ++j) acc[j] = 0.f;
            #pragma unroll
            for (int e = 0; e < E_; ++e){
                float r = r_s[b*E_ + e];
                #pragma unroll
                for (int j = 0; j < 8; ++j) acc[j] += r * w[e][j];
            }
            short8 ov;
            #pragma unroll
            for (int jj = 0; jj < 4; ++jj){
                unsigned int d;
                asm("v_cvt_pk_bf16_f32 %0, %1, %2" : "=v"(d) : "v"(acc[2*jj]), "v"(acc[2*jj+1]));
                ov[2*jj]   = (short)(d & 0xFFFF);
                ov[2*jj+1] = (short)(d >> 16);
            }
            *(short8*)(aggw + (((size_t)(b*COUT + o))*9 + tp)*CIN + cg*8) = ov;
        }
    }
}

// -------- 3) k_conv: R4 structure, NO setprio (A/B: scheduler starvation test) --------
__global__ __launch_bounds__(512, 2) void k_conv(
    const u16* __restrict__ aggw, const u16* __restrict__ xt2,
    const float* __restrict__ aggb, float* __restrict__ out)
{
    __shared__ __align__(16) u16 lds[65536];   // 2 buf x (A 256x64 + B 256x64) bf16

    int orig = blockIdx.x;
    int bid = (orig & 7)*32 + (orig >> 3);     // bijective XCD swizzle

    int b  = bid >> 4;
    int nt = bid & 15;
    int y0 = nt << 2;

    int t = threadIdx.x;
    int lane = t & 63;
    int w = t >> 6;
    int wm = (w >> 2) << 7;
    int wn = (w & 3) << 6;
    int l16 = lane & 15;
    int kh4 = lane >> 4;
    int sw  = l16 & 7;

    int tr = t >> 3;
    int tc = t & 7;
    int sc = tc ^ (tr & 7);

    const u16* aSrc = aggw + (size_t)b*COUT*9*CIN + (size_t)tr*KTOT + sc*8;
    const u16* bSrc = xt2 + ((size_t)b*PPIX + (size_t)y0*HP + tr)*CIN + sc*8;

    f32x4 acc[8][4];
    #pragma unroll
    for (int i = 0; i < 8; ++i)
        #pragma unroll
        for (int j = 0; j < 4; ++j){
            f32x4 z = {0.f,0.f,0.f,0.f};
            acc[i][j] = z;
        }

    auto stage = [&](int kt, int bufn){
        int tap = kt >> 2;
        int c0  = (kt & 3) << 6;
        int kh  = tap / 3, kw = tap - kh*3;
        const u16* a0 = aSrc + tap*CIN + c0;
        const u16* b0 = bSrc + (kh*HP + kw)*CIN + c0;
        u16* dA = lds + bufn*32768 + w*512;
        u16* dB = dA + 16384;
        #pragma unroll
        for (int i = 0; i < 4; ++i)
            gload(a0 + (size_t)i*64*KTOT, dA + i*4096);
        #pragma unroll
        for (int i = 0; i < 4; ++i)
            gload(b0 + (size_t)i*HP*CIN, dB + i*4096);
    };

    int ck0 = ((kh4    ) ^ sw) * 8;
    int ck1 = ((kh4 | 4) ^ sw) * 8;

    stage(0, 0);
    __syncthreads();

    int buf = 0;
    #pragma unroll 2
    for (int kt = 0; kt < NKT; ++kt){
        const u16* LA = lds + buf*32768;
        const u16* LB = LA + 16384;

        bf16x8 af[2][4][2];    // [qm][mf][khalf]
        bf16x8 bfr[2][2][2];   // [qn][nf][khalf]

        #pragma unroll
        for (int mf = 0; mf < 4; ++mf){
            int ro = (wm + mf*16 + l16) * 64;
            af[0][mf][0] = *(const bf16x8*)(LA + ro + ck0);
            af[0][mf][1] = *(const bf16x8*)(LA + ro + ck1);
        }
        #pragma unroll
        for (int nf = 0; nf < 2; ++nf){
            int ro = (wn + nf*16 + l16) * 64;
            bfr[0][nf][0] = *(const bf16x8*)(LB + ro + ck0);
            bfr[0][nf][1] = *(const bf16x8*)(LB + ro + ck1);
        }

        if (kt < NKT-1) stage(kt+1, buf^1);

        #pragma unroll
        for (int nf = 0; nf < 2; ++nf){
            int ro = (wn + 32 + nf*16 + l16) * 64;
            bfr[1][nf][0] = *(const bf16x8*)(LB + ro + ck0);
            bfr[1][nf][1] = *(const bf16x8*)(LB + ro + ck1);
        }
        #pragma unroll
        for (int mf = 0; mf < 4; ++mf){
            int ro = (wm + 64 + mf*16 + l16) * 64;
            af[1][mf][0] = *(const bf16x8*)(LA + ro + ck0);
            af[1][mf][1] = *(const bf16x8*)(LA + ro + ck1);
        }

        // MFMA clusters WITHOUT setprio: let the CU scheduler round-robin waves so
        // other waves' ds_reads issue under this wave's MFMA stream (overlap test)
        #pragma unroll
        for (int qm = 0; qm < 2; ++qm)
            #pragma unroll
            for (int qn = 0; qn < 2; ++qn){
                #pragma unroll
                for (int mf = 0; mf < 4; ++mf)
                    #pragma unroll
                    for (int nf = 0; nf < 2; ++nf){
                        acc[qm*4+mf][qn*2+nf] = __builtin_amdgcn_mfma_f32_16x16x32_bf16(
                            af[qm][mf][0], bfr[qn][nf][0], acc[qm*4+mf][qn*2+nf], 0, 0, 0);
                        acc[qm*4+mf][qn*2+nf] = __builtin_amdgcn_mfma_f32_16x16x32_bf16(
                            af[qm][mf][1], bfr[qn][nf][1], acc[qm*4+mf][qn*2+nf], 0, 0, 0);
                    }
            }

        __syncthreads();
        buf ^= 1;
    }

    const float* ab = aggb + b*COUT;
    float* outp = out + ((size_t)b*COUT)*NPIX + nt*256;
    #pragma unroll
    for (int mf8 = 0; mf8 < 8; ++mf8){
        #pragma unroll
        for (int v = 0; v < 4; ++v){
            int r = wm + mf8*16 + (kh4 << 2) + v;
            float bias_r = ab[r];
            float* orow = outp + (size_t)r*NPIX;
            #pragma unroll
            for (int nf = 0; nf < 4; ++nf)
                orow[wn + nf*16 + l16] = acc[mf8][nf][v] + bias_r;
        }
    }
}

extern "C" void kernel_launch(void* const* d_in, const int* in_sizes, int n_in,
                              void* d_out, int out_size, void* d_ws, size_t ws_size,
                              hipStream_t stream)
{
    const float* x      = (const float*)d_in[0];
    const float* weight = (const float*)d_in[1];
    const float* bias   = (const float*)d_in[2];
    const float* rw     = (const float*)d_in[3];
    const float* rb     = (const float*)d_in[4];
    float* out = (float*)d_out;

    char* ws = (char*)d_ws;
    u16*   aggw    = (u16*)(ws);                          // 18,874,368 B
    u16*   xt2     = (u16*)(ws + 18874368);               // 35,684,352 B (halo 66x66)
    float* pooled  = (float*)(ws + 54558720);             // 16 KB
    float* aggb    = (float*)(ws + 54558720 + 16384);     // 16 KB

    hipMemsetAsync(pooled, 0, B_*CIN*sizeof(float), stream);
    k_xt   <<<4096, 256, 0, stream>>>(x, xt2, pooled);
    k_aggw <<<COUT, 576, 0, stream>>>(weight, pooled, rw, rb, bias, aggw, aggb);
    k_conv <<<256,  512, 0, stream>>>(aggw, xt2, aggb, out);
}